// Round 3
// baseline (419.099 us; speedup 1.0000x reference)
//
#include <hip/hip_runtime.h>

// SelfAttention: B=8, S=2048, D=1024, U=1024, fp32 in/out.
// R7: de-barrier the 256^2 pipeline. R5/R6 post-mortem: at 1 block/CU the
// per-phase [reads|bar|lgkm0|MFMA|bar] lockstep SERIALIZES LDS drain and MFMA
// CU-wide (reads(p+1) can't issue until every wave's MFMA(p) is done) ->
// 6100 cyc/tile vs 2483 MFMA-need, MfmaUtil 36%. R4's 128^2 won via 2
// blocks/CU free-running overlap (m114), which 128KB LDS forfeits.
// Fix: ONE vmcnt(0)+barrier per K-tile; the whole 24-ds_read + 64-MFMA tile
// body is a single compiler-scheduled region (compiler emits fine-grained
// lgkmcnt interleave on its own -- no asm lgkm / sched_barrier / setprio to
// defeat it). 8 waves free-run within the tile: one wave's LDS drain hides
// under another's MFMAs. Stage all 4 half-tiles of t+1 at top of tile t;
// issue->vmcnt(0) distance = full tile body (~3000 cyc) >> HBM latency.
//
// Hazards: stages at tile t write parity (t+1)&1; its last readers (tile t-1)
// drained before their consuming MFMAs, which precede the end-of-(t-1)
// barrier -> WAR safe. vmcnt(0)+barrier at end of t publishes t+1 for all
// waves. Swizzle (slot (row,c8) holds global colgroup c8^(row&7)) unchanged,
// verified conflict-free.
// Workspace: 33.6(Xh) + 6.3(WbT) + 33.6*3(QKV) + 67.1(P) = 207.7 MB

typedef _Float16 half8  __attribute__((ext_vector_type(8)));
typedef _Float16 half4v __attribute__((ext_vector_type(4)));
typedef _Float16 half2v __attribute__((ext_vector_type(2)));
typedef float    floatx4 __attribute__((ext_vector_type(4)));

// ---- async stage: one 128x64 fp16 half-tile (16 KB) -> LDS, swizzled ----
// 2 global_load_lds_dwordx4 per thread (512 threads x 2 x 16B = 16 KB).
__device__ __forceinline__ void stage_ht(const _Float16* __restrict__ src, int ld,
                                         _Float16* __restrict__ dst, int wave, int lane) {
#pragma unroll
    for (int i = 0; i < 2; ++i) {
        int q = wave * 2 + i;            // 16 wave-chunks of 1 KB
        int c = q * 64 + lane;           // 8-elem chunk id in [0,1024)
        int row = c >> 3, c8 = c & 7;
        int cg = c8 ^ (row & 7);         // pre-swizzled global source colgroup
        __builtin_amdgcn_global_load_lds(
            (const __attribute__((address_space(1))) unsigned int*)(src + (size_t)row * ld + cg * 8),
            (__attribute__((address_space(3))) unsigned int*)(dst + q * 512),
            16, 0, 0);
    }
}

// pk-add sum of 8 halves -> float
__device__ __forceinline__ float sum8h(half8 a) {
    union { half8 v; half2v h2[4]; } u; u.v = a;
    half2v s0 = u.h2[0] + u.h2[1];
    half2v s1 = u.h2[2] + u.h2[3];
    half2v s  = s0 + s1;
    return (float)s[0] + (float)s[1];
}

#define BARF() do { __builtin_amdgcn_s_barrier(); asm volatile("" ::: "memory"); } while (0)

#define SA_(T, h) stage_ht(A + (size_t)((h) * 128) * lda + (size_t)(T) * 64, lda, \
                           ShA + (((T) & 1) * 2 + (h)) * 8192, wave, lane)
#define SB_(T, h) stage_ht(B + (size_t)((h) * 128) * ldb + (size_t)(T) * 64, ldb, \
                           ShB + (((T) & 1) * 2 + (h)) * 8192, wave, lane)

// ---- one K-tile compute body: 24 ds_read_b128 + 64 MFMA, compiler-scheduled ----
template<bool RSUM>
__device__ __forceinline__ void tile_body(const _Float16* __restrict__ As,
                                          const _Float16* __restrict__ Bs,
                                          int rb, int l15, int q4,
                                          floatx4 (&acc)[8][4], float (&rsum)[8]) {
#pragma unroll
    for (int kk = 0; kk < 2; ++kk) {
        half8 bf[4];
#pragma unroll
        for (int j = 0; j < 4; ++j) {
            int rr = rb + j * 16 + l15;
            int cg = (kk * 4 + q4) ^ (rr & 7);
            bf[j] = *(const half8*)(Bs + rr * 64 + cg * 8);
        }
#pragma unroll
        for (int i = 0; i < 8; ++i) {
            int rr = i * 16 + l15;
            int cg = (kk * 4 + q4) ^ (rr & 7);
            half8 af = *(const half8*)(As + rr * 64 + cg * 8);
            if (RSUM) rsum[i] += sum8h(af);
#pragma unroll
            for (int j = 0; j < 4; ++j)
                acc[i][j] = __builtin_amdgcn_mfma_f32_16x16x32_f16(
                    af, bf[j], acc[i][j], 0, 0, 0);
        }
    }
}

// ---- shared 256x256-tile GEMM main loop (1 barrier per K-tile) ----
// A: 256 rows (caller pre-offset by m0) x K, row-major ld=lda
// B: 256 rows (caller pre-offset by n0) x K, row-major ld=ldb
template<bool RSUM>
__device__ __forceinline__ void gemm8p(const _Float16* __restrict__ A, int lda,
                                       const _Float16* __restrict__ B, int ldb,
                                       int K, _Float16* __restrict__ ShA,
                                       _Float16* __restrict__ ShB,
                                       int wave, int lane,
                                       floatx4 (&acc)[8][4], float (&rsum)[8]) {
    const int wm = wave >> 2, wn = wave & 3;
    const int l15 = lane & 15, q4 = lane >> 4;
    const int NT = K >> 6;

    // prologue: stage tile 0, drain, publish
    SB_(0, 0); SB_(0, 1); SA_(0, 0); SA_(0, 1);
    asm volatile("s_waitcnt vmcnt(0)" ::: "memory");
    BARF();

    for (int t = 0; t < NT; ++t) {
        const _Float16* As = ShA + (t & 1) * 16384 + wm * 8192;
        const _Float16* Bs = ShB + (t & 1) * 16384 + (wn >> 1) * 8192;

        // stage ALL of tile t+1 into the other-parity buffer (WAR-safe: its
        // previous readers drained before the end-of-(t-1) barrier)
        if (t + 1 < NT) { SA_(t + 1, 0); SA_(t + 1, 1); SB_(t + 1, 0); SB_(t + 1, 1); }

        tile_body<RSUM>(As, Bs, (wn & 1) * 64, l15, q4, acc, rsum);

        if (t + 1 < NT) {
            asm volatile("s_waitcnt vmcnt(0)" ::: "memory");  // ~free: issued a full tile ago
            BARF();                                           // publish tile t+1
        }
    }
}

// ---- kernel 0: cast X fp32 -> fp16 ----
__global__ void cast_x(const float* __restrict__ X, _Float16* __restrict__ Xh) {
    size_t i = ((size_t)blockIdx.x * 256 + threadIdx.x) * 8;
    float4 v0 = *(const float4*)(X + i);
    float4 v1 = *(const float4*)(X + i + 4);
    half8 hh;
    hh[0] = (_Float16)v0.x; hh[1] = (_Float16)v0.y; hh[2] = (_Float16)v0.z; hh[3] = (_Float16)v0.w;
    hh[4] = (_Float16)v1.x; hh[5] = (_Float16)v1.y; hh[6] = (_Float16)v1.z; hh[7] = (_Float16)v1.w;
    *(half8*)(Xh + i) = hh;
}

// ---- kernel 1: transpose-cast weights to fp16 ----
__global__ void prep_weights(const float* __restrict__ Wq, const float* __restrict__ Wk,
                             const float* __restrict__ Wv, _Float16* __restrict__ WbT) {
    int g = blockIdx.z;
    const float* W = (g == 0) ? Wq : (g == 1) ? Wk : Wv;
    __shared__ float tile[32][33];
    int u0 = blockIdx.x * 32, d0 = blockIdx.y * 32;
    int tx = threadIdx.x & 31, ty = threadIdx.x >> 5;
#pragma unroll
    for (int i = 0; i < 32; i += 8)
        tile[ty + i][tx] = W[(size_t)(d0 + ty + i) * 1024 + (u0 + tx)];
    __syncthreads();
#pragma unroll
    for (int i = 0; i < 32; i += 8)
        WbT[(size_t)g * 1024 * 1024 + (size_t)(u0 + ty + i) * 1024 + (d0 + tx)] =
            (_Float16)tile[tx][ty + i];
}

// ---- kernel 2: fused QKV projection (256^2 tiles) ----
// grid (12,64): blockIdx.x>>2 selects Q/K/V (block-uniform), &3 is the u-tile.
__global__ __launch_bounds__(512, 2)
void qkv_gemm(const _Float16* __restrict__ Xh, const _Float16* __restrict__ WbT,
              _Float16* __restrict__ Qh, _Float16* __restrict__ Kh,
              _Float16* __restrict__ Vt) {
    __shared__ __align__(16) _Float16 ShA[32768];
    __shared__ __align__(16) _Float16 ShB[32768];
    int t = threadIdx.x;
    int lane = t & 63, wave = t >> 6;
    int wm = wave >> 2, wn = wave & 3;
    int l15 = lane & 15, q4 = lane >> 4;
    int which = blockIdx.x >> 2;            // 0=Q 1=K 2=V
    int u0 = (blockIdx.x & 3) * 256;
    int m0 = blockIdx.y * 256;
    const _Float16* A = Xh + (size_t)m0 * 1024;
    const _Float16* B = WbT + (size_t)which * 1024 * 1024 + (size_t)u0 * 1024;
    floatx4 acc[8][4] = {};
    float rsum[8] = {};
    gemm8p<false>(A, 1024, B, 1024, 1024, ShA, ShB, wave, lane, acc, rsum);

    int bz = m0 >> 11;                       // batch (256-row tiles never straddle)
    int sbase = (m0 & 2047) + wm * 128;
    if (which < 2) {
        _Float16* db = (which ? Kh : Qh) + (size_t)bz * 2048 * 1024;
#pragma unroll
        for (int i = 0; i < 8; ++i)
#pragma unroll
            for (int j = 0; j < 4; ++j)
#pragma unroll
                for (int r = 0; r < 4; ++r) {
                    int s = sbase + i * 16 + q4 * 4 + r;
                    int u = u0 + wn * 64 + j * 16 + l15;
                    db[(size_t)s * 1024 + u] = (_Float16)acc[i][j][r];
                }
    } else {
        _Float16* vb = Vt + (size_t)bz * 1024 * 2048;
#pragma unroll
        for (int i = 0; i < 8; ++i)
#pragma unroll
            for (int j = 0; j < 4; ++j) {
                int s = sbase + i * 16 + q4 * 4;          // 4 consecutive s
                int u = u0 + wn * 64 + j * 16 + l15;
                half4v pk;
#pragma unroll
                for (int r = 0; r < 4; ++r) pk[r] = (_Float16)acc[i][j][r];
                *(half4v*)(vb + (size_t)u * 2048 + s) = pk;  // 8B aligned
            }
    }
}

// ---- kernel 3: scores (256^2 tiles), epilogue = exp + store ----
__global__ __launch_bounds__(512, 2)
void scores_gemm(const _Float16* __restrict__ Qh, const _Float16* __restrict__ Kh,
                 _Float16* __restrict__ P) {
    __shared__ __align__(16) _Float16 ShA[32768];
    __shared__ __align__(16) _Float16 ShB[32768];
    int t = threadIdx.x;
    int lane = t & 63, wave = t >> 6;
    int wm = wave >> 2, wn = wave & 3;
    int l15 = lane & 15, q4 = lane >> 4;
    int m0 = blockIdx.y * 256, n0 = blockIdx.x * 256;
    int batch = blockIdx.z;
    const _Float16* A = Qh + (size_t)batch * 2048 * 1024 + (size_t)m0 * 1024;
    const _Float16* B = Kh + (size_t)batch * 2048 * 1024 + (size_t)n0 * 1024;
    floatx4 acc[8][4] = {};
    float rsum[8] = {};
    gemm8p<false>(A, 1024, B, 1024, 1024, ShA, ShB, wave, lane, acc, rsum);

    _Float16* Pb = P + (size_t)batch * 2048 * 2048;
#pragma unroll
    for (int i = 0; i < 8; ++i)
#pragma unroll
        for (int j = 0; j < 4; ++j)
#pragma unroll
            for (int r = 0; r < 4; ++r) {
                int m = m0 + wm * 128 + i * 16 + q4 * 4 + r;
                int n = n0 + wn * 64 + j * 16 + l15;
                Pb[(size_t)m * 2048 + n] = (_Float16)__expf(acc[i][j][r] * 0.03125f);
            }
}

// ---- kernel 4: P @ V (256^2 tiles) with inline rowsum + normalization ----
__global__ __launch_bounds__(512, 2)
void pv_gemm(const _Float16* __restrict__ P, const _Float16* __restrict__ Vt,
             float* __restrict__ out) {
    __shared__ __align__(16) _Float16 ShA[32768];
    __shared__ __align__(16) _Float16 ShB[32768];
    int t = threadIdx.x;
    int lane = t & 63, wave = t >> 6;
    int wm = wave >> 2, wn = wave & 3;
    int l15 = lane & 15, q4 = lane >> 4;
    int m0 = blockIdx.y * 256, n0 = blockIdx.x * 256;
    int batch = blockIdx.z;
    const _Float16* A = P + (size_t)batch * 2048 * 2048 + (size_t)m0 * 2048;
    const _Float16* B = Vt + (size_t)batch * 1024 * 2048 + (size_t)n0 * 2048;
    floatx4 acc[8][4] = {};
    float rsum[8] = {};
    gemm8p<true>(A, 2048, B, 2048, 2048, ShA, ShB, wave, lane, acc, rsum);

    // merge the 4 q4 k-slices: lanes sharing l15 hold partials of the same row
    float rsumf[8];
#pragma unroll
    for (int i = 0; i < 8; ++i) {
        float v = rsum[i] + __shfl_xor(rsum[i], 16);
        rsumf[i] = v + __shfl_xor(v, 32);   // full rowsum of row i*16+l15
    }
    float* ob = out + (size_t)batch * 2048 * 1024;
#pragma unroll
    for (int i = 0; i < 8; ++i)
#pragma unroll
        for (int r = 0; r < 4; ++r) {
            int rloc = q4 * 4 + r;                       // C/D row within 16x16
            float inv = 1.0f / __shfl(rsumf[i], rloc);   // lane rloc holds it
            int m = m0 + wm * 128 + i * 16 + rloc;
#pragma unroll
            for (int j = 0; j < 4; ++j) {
                int n = n0 + wn * 64 + j * 16 + l15;
                ob[(size_t)m * 1024 + n] = acc[i][j][r] * inv;
            }
        }
}

extern "C" void kernel_launch(void* const* d_in, const int* in_sizes, int n_in,
                              void* d_out, int out_size, void* d_ws, size_t ws_size,
                              hipStream_t stream) {
    const float* X  = (const float*)d_in[0];
    const float* Wq = (const float*)d_in[1];
    const float* Wk = (const float*)d_in[2];
    const float* Wv = (const float*)d_in[3];
    float* out = (float*)d_out;

    char* ws = (char*)d_ws;
    size_t off = 0;
    _Float16* Xh  = (_Float16*)(ws + off); off += (size_t)8 * 2048 * 1024 * 2;
    _Float16* WbT = (_Float16*)(ws + off); off += (size_t)3 * 1024 * 1024 * 2;
    _Float16* Qh  = (_Float16*)(ws + off); off += (size_t)8 * 2048 * 1024 * 2;
    _Float16* Kh  = (_Float16*)(ws + off); off += (size_t)8 * 2048 * 1024 * 2;
    _Float16* Vt  = (_Float16*)(ws + off); off += (size_t)8 * 1024 * 2048 * 2;
    _Float16* P   = (_Float16*)(ws + off); off += (size_t)8 * 2048 * 2048 * 2;

    cast_x      <<<dim3(8192, 1, 1), 256, 0, stream>>>(X, Xh);
    prep_weights<<<dim3(32, 32, 3), 256, 0, stream>>>(Wq, Wk, Wv, WbT);
    qkv_gemm    <<<dim3(12, 64, 1), 512, 0, stream>>>(Xh, WbT, Qh, Kh, Vt);
    scores_gemm <<<dim3(8, 8, 8),   512, 0, stream>>>(Qh, Kh, P);
    pv_gemm     <<<dim3(4, 8, 8),   512, 0, stream>>>(P, Vt, out);
}